// Round 15
// baseline (128.377 us; speedup 1.0000x reference)
//
#include <hip/hip_runtime.h>
#include <float.h>

#define VOCAB 8192
#define DIM 64
#define NQ 32768
#define CHUNK 64                    // centroids staged per LDS buffer
#define THREADS 256
#define QPB 64                      // queries per block (16 per wave, t=1)
#define NSLICE 4

typedef __attribute__((ext_vector_type(8))) _Float16 half8;
typedef __attribute__((ext_vector_type(4))) float f32x4;

#define LO_SCALE 4096.0f
#define LO_INV   2.44140625e-4f     // 1/4096

// ---------------- c2h[c] = -0.5 * ||vocab[c]||^2 ----------------
__global__ __launch_bounds__(256) void c2_kernel(const float* __restrict__ vocab,
                                                 float* __restrict__ c2h) {
    int c = blockIdx.x * 256 + threadIdx.x;
    const float4* row = (const float4*)(vocab + (size_t)c * DIM);
    float a0 = 0.f, a1 = 0.f, a2 = 0.f, a3 = 0.f;
#pragma unroll
    for (int k = 0; k < DIM / 4; ++k) {
        float4 v = row[k];
        a0 = fmaf(v.x, v.x, a0); a1 = fmaf(v.y, v.y, a1);
        a2 = fmaf(v.z, v.z, a2); a3 = fmaf(v.w, v.w, a3);
    }
    c2h[c] = -0.5f * ((a0 + a1) + (a2 + a3));
}

// ---------------- split fp32 -> f16 hi + f16 lo*4096 ----------------
__global__ __launch_bounds__(256) void split_kernel(const float* __restrict__ src,
                                                    _Float16* __restrict__ hi,
                                                    _Float16* __restrict__ lo) {
    int t = blockIdx.x * 256 + threadIdx.x;     // one thread per 8 elements
    const float4* s = (const float4*)(src + (size_t)t * 8);
    float4 f0 = s[0], f1 = s[1];
    float x[8] = {f0.x, f0.y, f0.z, f0.w, f1.x, f1.y, f1.z, f1.w};
    half8 h, l;
#pragma unroll
    for (int j = 0; j < 8; ++j) {
        _Float16 hh = (_Float16)x[j];
        h[j] = hh;
        l[j] = (_Float16)((x[j] - (float)hh) * LO_SCALE);   // scaled lo: stays normal
    }
    *(half8*)(hi + (size_t)t * 8) = h;
    *(half8*)(lo + (size_t)t * 8) = l;
}

// async global->LDS; LDS dest = uniform base + lane*size (implicit). size literal.
__device__ __forceinline__ void gload_lds16(const void* g, void* lds_dst) {
    __builtin_amdgcn_global_load_lds(
        (const __attribute__((address_space(1))) void*)g,
        (__attribute__((address_space(3))) void*)lds_dst, 16, 0, 0);
}
__device__ __forceinline__ void gload_lds4(const void* g, void* lds_dst) {
    __builtin_amdgcn_global_load_lds(
        (const __attribute__((address_space(1))) void*)g,
        (__attribute__((address_space(3))) void*)lds_dst, 4, 0, 0);
}

// ---------------- main: MFMA GEMM + fused argmin (argmax of dot - c2/2) ----------------
// r8's body (counted vmcnt(5) + setprio + 2 barriers/chunk) — the proven
// schedule — at a NEW allocator operating point:
//
// OCCUPANCY/ALLOCATOR LAW (r2-r14): hint=N caps waves/SIMD at N AND splits
// the 512-reg budget evenly arch/acc (hint=2 -> 128, hint=3 -> 84 [r10],
// hint=4 -> 64 [r3/r5]). r8's t=4 tile (124 arch) only fits hint=2 ->
// 2 waves/SIMD -> MfmaUtil plateau 45% across 5 schedule variants (r12-r14).
// THIS ROUND: shrink the tile to t=1 (16 q/wave, ~60-75 arch regs <= 84)
// so hint=3 fits WITHOUT spill -> 3 waves/SIMD, each from a DIFFERENT block
// (1 wave/block/SIMD) so barriers never align across the 3 streams.
// Cost: vocab staged 4x more (1 GB L2 reads, overlapped; vocab L2-resident).
// Tripwire: VGPR<=84 & WRITE ~1MB (r10's spill signature was 759MB WRITE).
__global__ __launch_bounds__(THREADS, 3)
void argmin_mfma(const float* __restrict__ patches,
                 const _Float16* __restrict__ vhi,
                 const _Float16* __restrict__ vlo,
                 const float* __restrict__ c2g,     // holds -0.5*||c||^2
                 float* __restrict__ ws_best,
                 int*   __restrict__ ws_idx) {
    constexpr int CSLICE = VOCAB / NSLICE;
    constexpr int NCHUNK = CSLICE / CHUNK;
    // [buf0: hi 8K | lo 8K][buf1: hi 8K | lo 8K][c2 buf0 256B][c2 buf1 256B]
    __shared__ __align__(16) char smem[2 * 16384 + 2 * 256];

    const int tid   = threadIdx.x;
    const int lane  = tid & 63;
    const int w     = tid >> 6;                     // wave 0..3
    const int slice = blockIdx.x & (NSLICE - 1);    // XCD-aligned vocab slice
    const int qg    = blockIdx.x / NSLICE;
    const int qbase = qg * QPB + w * 16;            // this wave's 16 queries
    const int cbase = slice * CSLICE;

    // ---- load + split this wave's A fragment (16 queries) into registers ----
    const int arow = lane & 15;                 // query row within 16-tile
    const int akc  = lane >> 4;                 // k-chunk 0..3 (8 elems each)
    half8 Ah[2], Al[2];
#pragma unroll
    for (int ks = 0; ks < 2; ++ks) {
        const float* p = patches + (size_t)(qbase + arow) * DIM + ks * 32 + akc * 8;
        float4 f0 = *(const float4*)p;
        float4 f1 = *(const float4*)(p + 4);
        float x[8] = {f0.x, f0.y, f0.z, f0.w, f1.x, f1.y, f1.z, f1.w};
        half8 h, l;
#pragma unroll
        for (int j = 0; j < 8; ++j) {
            _Float16 hh = (_Float16)x[j];
            h[j] = hh;
            l[j] = (_Float16)((x[j] - (float)hh) * LO_SCALE);
        }
        Ah[ks] = h; Al[ks] = l;
    }

    // staging source offset (elems): row = (lane>>3), col16' = (lane&7)^(lane>>3)
    const int s_srcoff = ((lane >> 3) * DIM) + (((lane & 7) ^ (lane >> 3)) * 8);
    // frag ds_read byte offsets: row fr, swizzled k-chunk
    const int fr = lane & 15;
    const int fx = fr & 7;
    const int b_off0 = fr * 128 + (((0 * 4 + akc) ^ fx) * 16);   // kstep 0
    const int b_off1 = fr * 128 + (((1 * 4 + akc) ^ fx) * 16);   // kstep 1

    // stage chunk ch into buffer buf: 4x 1KB hi/lo + 256B c2 = 5 VMEM/wave
    auto stage = [&](int ch, int buf) {
        const size_t crow = (size_t)(cbase + ch * CHUNK) * DIM;
        char* dst = smem + buf * 16384;
#pragma unroll
        for (int j = 0; j < 2; ++j) {
            int r0 = (w + 4 * j) * 8;           // 8 rows = 1KB per instr
            gload_lds16(vhi + crow + (size_t)r0 * DIM + s_srcoff, dst + r0 * 128);
            gload_lds16(vlo + crow + (size_t)r0 * DIM + s_srcoff, dst + 8192 + r0 * 128);
        }
        // all 4 waves duplicate the same 256B c2 row (identical data, benign)
        gload_lds4(c2g + cbase + ch * CHUNK + lane, smem + 32768 + buf * 256);
    };

    float best[4];
    int   bidx[4];
#pragma unroll
    for (int j = 0; j < 4; ++j) { best[j] = -FLT_MAX; bidx[j] = 0; }

    stage(0, 0);

    for (int ch = 0; ch < NCHUNK; ++ch) {
        const int cur = ch & 1;
        if (ch + 1 < NCHUNK) {
            stage(ch + 1, cur ^ 1);
            // own ch-loads done; ch+1's 5 stay in flight across the barrier
            asm volatile("s_waitcnt vmcnt(5)" ::: "memory");
        } else {
            asm volatile("s_waitcnt vmcnt(0)" ::: "memory");
        }
        __builtin_amdgcn_s_barrier();   // all waves' ch staging landed

        const char*  hib = smem + cur * 16384;
        const char*  lob = hib + 8192;
        const float* c2b = (const float*)(smem + 32768 + cur * 256);
        const int cb = cbase + ch * CHUNK;

#pragma unroll
        for (int nt = 0; nt < 4; ++nt) {
            const int rt = nt * 16;
            half8 Bh0 = *(const half8*)(hib + rt * 128 + b_off0);
            half8 Bh1 = *(const half8*)(hib + rt * 128 + b_off1);
            half8 Bl0 = *(const half8*)(lob + rt * 128 + b_off0);
            half8 Bl1 = *(const half8*)(lob + rt * 128 + b_off1);
            const float c2h = c2b[rt + fr];         // -0.5*||c||^2 (LDS)
            const int  cidx = cb + rt + fr;
            __builtin_amdgcn_s_setprio(1);
            f32x4 am = {c2h, c2h, c2h, c2h};        // hi*hi, seeded with -c2/2
            f32x4 al = {0.f, 0.f, 0.f, 0.f};        // cross terms, scale 4096
            am = __builtin_amdgcn_mfma_f32_16x16x32_f16(Ah[0], Bh0, am, 0, 0, 0);
            am = __builtin_amdgcn_mfma_f32_16x16x32_f16(Ah[1], Bh1, am, 0, 0, 0);
            al = __builtin_amdgcn_mfma_f32_16x16x32_f16(Ah[0], Bl0, al, 0, 0, 0);
            al = __builtin_amdgcn_mfma_f32_16x16x32_f16(Ah[1], Bl1, al, 0, 0, 0);
            al = __builtin_amdgcn_mfma_f32_16x16x32_f16(Al[0], Bh0, al, 0, 0, 0);
            al = __builtin_amdgcn_mfma_f32_16x16x32_f16(Al[1], Bh1, al, 0, 0, 0);
            __builtin_amdgcn_s_setprio(0);
#pragma unroll
            for (int j = 0; j < 4; ++j) {
                float val = fmaf(al[j], LO_INV, am[j]);     // dot - c2/2
                // argmax == argmin of distance; strict > keeps FIRST (lowest c) on ties
                if (val > best[j]) { best[j] = val; bidx[j] = cidx; }
            }
        }
        __builtin_amdgcn_s_barrier();   // all reads of buf[cur] done before overwrite
    }

    // ---- butterfly argmax-merge across the 16 column-lanes of each row-group ----
#pragma unroll
    for (int j = 0; j < 4; ++j) {
        float b = best[j]; int bi = bidx[j];
#pragma unroll
        for (int d = 1; d < 16; d <<= 1) {
            float ob = __shfl_xor(b, d, 64);
            int   oi = __shfl_xor(bi, d, 64);
            if (ob > b || (ob == b && oi < bi)) { b = ob; bi = oi; }
        }
        best[j] = b; bidx[j] = bi;
    }

    if ((lane & 15) == 0) {
        const int rg = lane >> 4;
#pragma unroll
        for (int j = 0; j < 4; ++j) {
            int q = qbase + rg * 4 + j;
            ws_best[(size_t)slice * NQ + q] = best[j];
            ws_idx [(size_t)slice * NQ + q] = bidx[j];
        }
    }
}

// ---------------- merge slices (max of val, lower index on ties) ----------------
__global__ __launch_bounds__(256) void merge_kernel(const float* __restrict__ ws_best,
                                                    const int* __restrict__ ws_idx,
                                                    int* __restrict__ out) {
    int q = blockIdx.x * 256 + threadIdx.x;
    float b = ws_best[q]; int bi = ws_idx[q];
#pragma unroll
    for (int s = 1; s < NSLICE; ++s) {
        float v = ws_best[(size_t)s * NQ + q];
        int  vi = ws_idx[(size_t)s * NQ + q];
        if (v > b || (v == b && vi < bi)) { b = v; bi = vi; }
    }
    out[q] = bi;
}

extern "C" void kernel_launch(void* const* d_in, const int* in_sizes, int n_in,
                              void* d_out, int out_size, void* d_ws, size_t ws_size,
                              hipStream_t stream) {
    const float* patches = (const float*)d_in[0];   // [32768][64] fp32
    const float* vocab   = (const float*)d_in[1];   // [8192][64] fp32
    char* ws = (char*)d_ws;
    float*    c2    = (float*)ws;                                   // 32 KB
    _Float16* vhi   = (_Float16*)(ws + 32768);                      // 1 MB
    _Float16* vlo   = (_Float16*)(ws + 32768 + 1048576);            // 1 MB
    float*    wbest = (float*)(ws + 32768 + 2097152);               // 512 KB
    int*      widx  = (int*)  (ws + 32768 + 2097152 + 524288);      // 512 KB
    int* out = (int*)d_out;

    c2_kernel   <<<VOCAB / 256, 256, 0, stream>>>(vocab, c2);
    split_kernel<<<(VOCAB * DIM / 8) / 256, 256, 0, stream>>>(vocab, vhi, vlo);
    argmin_mfma <<<(NQ / QPB) * NSLICE, THREADS, 0, stream>>>(patches, vhi, vlo, c2, wbest, widx);
    merge_kernel<<<NQ / 256, 256, 0, stream>>>(wbest, widx, out);
}

// Round 16
// 109.919 us; speedup vs baseline: 1.1679x; 1.1679x over previous
//
#include <hip/hip_runtime.h>
#include <float.h>

#define VOCAB 8192
#define DIM 64
#define NQ 32768
#define CHUNK 32                    // centroids staged per LDS buffer (1-wave blocks)
#define THREADS 64                  // ONE wave per block
#define QPB 64                      // queries per block (= per wave, t=4)
#define NSLICE 4

typedef __attribute__((ext_vector_type(8))) _Float16 half8;
typedef __attribute__((ext_vector_type(4))) float f32x4;

#define LO_SCALE 4096.0f
#define LO_INV   2.44140625e-4f     // 1/4096

// ---------------- c2h[c] = -0.5 * ||vocab[c]||^2 ----------------
__global__ __launch_bounds__(256) void c2_kernel(const float* __restrict__ vocab,
                                                 float* __restrict__ c2h) {
    int c = blockIdx.x * 256 + threadIdx.x;
    const float4* row = (const float4*)(vocab + (size_t)c * DIM);
    float a0 = 0.f, a1 = 0.f, a2 = 0.f, a3 = 0.f;
#pragma unroll
    for (int k = 0; k < DIM / 4; ++k) {
        float4 v = row[k];
        a0 = fmaf(v.x, v.x, a0); a1 = fmaf(v.y, v.y, a1);
        a2 = fmaf(v.z, v.z, a2); a3 = fmaf(v.w, v.w, a3);
    }
    c2h[c] = -0.5f * ((a0 + a1) + (a2 + a3));
}

// ---------------- split fp32 -> f16 hi + f16 lo*4096 ----------------
__global__ __launch_bounds__(256) void split_kernel(const float* __restrict__ src,
                                                    _Float16* __restrict__ hi,
                                                    _Float16* __restrict__ lo) {
    int t = blockIdx.x * 256 + threadIdx.x;     // one thread per 8 elements
    const float4* s = (const float4*)(src + (size_t)t * 8);
    float4 f0 = s[0], f1 = s[1];
    float x[8] = {f0.x, f0.y, f0.z, f0.w, f1.x, f1.y, f1.z, f1.w};
    half8 h, l;
#pragma unroll
    for (int j = 0; j < 8; ++j) {
        _Float16 hh = (_Float16)x[j];
        h[j] = hh;
        l[j] = (_Float16)((x[j] - (float)hh) * LO_SCALE);   // scaled lo: stays normal
    }
    *(half8*)(hi + (size_t)t * 8) = h;
    *(half8*)(lo + (size_t)t * 8) = l;
}

// async global->LDS; LDS dest = uniform base + lane*size (implicit). size literal.
__device__ __forceinline__ void gload_lds16(const void* g, void* lds_dst) {
    __builtin_amdgcn_global_load_lds(
        (const __attribute__((address_space(1))) void*)g,
        (__attribute__((address_space(3))) void*)lds_dst, 16, 0, 0);
}
__device__ __forceinline__ void gload_lds4(const void* g, void* lds_dst) {
    __builtin_amdgcn_global_load_lds(
        (const __attribute__((address_space(1))) void*)g,
        (__attribute__((address_space(3))) void*)lds_dst, 4, 0, 0);
}

// ---------------- main: barrier-FREE 1-wave MFMA GEMM + fused argmin ----------------
// r15 post-mortem: more waves (t=1, 3/SIMD) raised occupancy 20->36% but
// LOST 24us — per-wave fixed overhead x4 swamped the TLP. r8's t=4
// amortization is right; its residual stall is LOCKSTEP: both waves/SIMD are
// barrier-synced siblings stalling on the same lgkm/barrier at the same time.
// THIS ROUND: 1-wave blocks. Each wave double-buffers its OWN 8.5KB LDS
// (CHUNK=32) and needs NO barriers — only its own counted vmcnt(9). The 2
// waves/SIMD now come from DIFFERENT blocks, free-running at drifting phases
// (m114 co-scheduling fills each other's bubbles). t=4 tile/regs/swizzle/
// 6-MFMA cluster/setprio all inherited verbatim from r8 (absmax-0-proven).
// Cost: staging VMEM x4 (~1GB from L2, overlapped; slice L2-resident).
// Tripwire: VGPR<=128 & WRITE ~1MB (spill signature = huge WRITE/FETCH).
__global__ __launch_bounds__(THREADS, 2)
void argmin_mfma(const float* __restrict__ patches,
                 const _Float16* __restrict__ vhi,
                 const _Float16* __restrict__ vlo,
                 const float* __restrict__ c2g,     // holds -0.5*||c||^2
                 float* __restrict__ ws_best,
                 int*   __restrict__ ws_idx) {
    constexpr int CSLICE = VOCAB / NSLICE;
    constexpr int NCHUNK = CSLICE / CHUNK;          // 64
    // [buf0: hi 4K | lo 4K][buf1: hi 4K | lo 4K][c2 buf0 256B][c2 buf1 256B]
    __shared__ __align__(16) char smem[2 * 8192 + 2 * 256];

    const int lane  = threadIdx.x & 63;
    const int slice = blockIdx.x & (NSLICE - 1);    // XCD-aligned vocab slice
    const int qg    = blockIdx.x / NSLICE;
    const int qbase = qg * QPB;                     // this wave's 64 queries
    const int cbase = slice * CSLICE;

    // ---- load + split this wave's A fragments (queries) into registers ----
    const int arow = lane & 15;                 // query row within 16-tile
    const int akc  = lane >> 4;                 // k-chunk 0..3 (8 elems each)
    half8 Ah[4][2], Al[4][2];
#pragma unroll
    for (int t = 0; t < 4; ++t)
#pragma unroll
        for (int ks = 0; ks < 2; ++ks) {
            const float* p = patches + (size_t)(qbase + t * 16 + arow) * DIM
                           + ks * 32 + akc * 8;
            float4 f0 = *(const float4*)p;
            float4 f1 = *(const float4*)(p + 4);
            float x[8] = {f0.x, f0.y, f0.z, f0.w, f1.x, f1.y, f1.z, f1.w};
            half8 h, l;
#pragma unroll
            for (int j = 0; j < 8; ++j) {
                _Float16 hh = (_Float16)x[j];
                h[j] = hh;
                l[j] = (_Float16)((x[j] - (float)hh) * LO_SCALE);
            }
            Ah[t][ks] = h; Al[t][ks] = l;
        }

    // staging source offset (elems): row = (lane>>3), col16' = (lane&7)^(lane>>3)
    const int s_srcoff = ((lane >> 3) * DIM) + (((lane & 7) ^ (lane >> 3)) * 8);
    // frag ds_read byte offsets: row fr, swizzled k-chunk
    const int fr = lane & 15;
    const int fx = fr & 7;
    const int b_off0 = fr * 128 + (((0 * 4 + akc) ^ fx) * 16);   // kstep 0
    const int b_off1 = fr * 128 + (((1 * 4 + akc) ^ fx) * 16);   // kstep 1

    // stage chunk ch into buffer buf: 4x hi + 4x lo (1KB each) + c2 = 9 VMEM
    auto stage = [&](int ch, int buf) {
        const size_t crow = (size_t)(cbase + ch * CHUNK) * DIM;
        char* dst = smem + buf * 8192;
#pragma unroll
        for (int j = 0; j < 4; ++j) {
            int r0 = j * 8;                     // 8 rows = 1KB per instr
            gload_lds16(vhi + crow + (size_t)r0 * DIM + s_srcoff, dst + r0 * 128);
            gload_lds16(vlo + crow + (size_t)r0 * DIM + s_srcoff, dst + 4096 + r0 * 128);
        }
        // lanes 32-63 duplicate c2[0..31] into unused LDS tail (avoids OOB)
        gload_lds4(c2g + cbase + ch * CHUNK + (lane & 31), smem + 16384 + buf * 256);
    };

    float best[4][4];
    int   bidx[4][4];
#pragma unroll
    for (int t = 0; t < 4; ++t)
#pragma unroll
        for (int j = 0; j < 4; ++j) { best[t][j] = -FLT_MAX; bidx[t][j] = 0; }

    stage(0, 0);

    for (int ch = 0; ch < NCHUNK; ++ch) {
        const int cur = ch & 1;
        if (ch + 1 < NCHUNK) {
            stage(ch + 1, cur ^ 1);
            // wait for ch's 9 oldest; ch+1's 9 stay in flight (no barrier needed:
            // this wave is the only reader of its LDS)
            asm volatile("s_waitcnt vmcnt(9)" ::: "memory");
        } else {
            asm volatile("s_waitcnt vmcnt(0)" ::: "memory");
        }

        const char*  hib = smem + cur * 8192;
        const char*  lob = hib + 4096;
        const float* c2b = (const float*)(smem + 16384 + cur * 256);
        const int cb = cbase + ch * CHUNK;

#pragma unroll
        for (int nt = 0; nt < 2; ++nt) {
            const int rt = nt * 16;
            half8 Bh0 = *(const half8*)(hib + rt * 128 + b_off0);
            half8 Bh1 = *(const half8*)(hib + rt * 128 + b_off1);
            half8 Bl0 = *(const half8*)(lob + rt * 128 + b_off0);
            half8 Bl1 = *(const half8*)(lob + rt * 128 + b_off1);
            const float c2h = c2b[rt + fr];         // -0.5*||c||^2 (LDS)
            const int  cidx = cb + rt + fr;
            __builtin_amdgcn_s_setprio(1);
#pragma unroll
            for (int t = 0; t < 4; ++t) {
                f32x4 am = {c2h, c2h, c2h, c2h};    // hi*hi, seeded with -c2/2
                f32x4 al = {0.f, 0.f, 0.f, 0.f};    // cross terms, scale 4096
                am = __builtin_amdgcn_mfma_f32_16x16x32_f16(Ah[t][0], Bh0, am, 0, 0, 0);
                am = __builtin_amdgcn_mfma_f32_16x16x32_f16(Ah[t][1], Bh1, am, 0, 0, 0);
                al = __builtin_amdgcn_mfma_f32_16x16x32_f16(Ah[t][0], Bl0, al, 0, 0, 0);
                al = __builtin_amdgcn_mfma_f32_16x16x32_f16(Ah[t][1], Bl1, al, 0, 0, 0);
                al = __builtin_amdgcn_mfma_f32_16x16x32_f16(Al[t][0], Bh0, al, 0, 0, 0);
                al = __builtin_amdgcn_mfma_f32_16x16x32_f16(Al[t][1], Bh1, al, 0, 0, 0);
#pragma unroll
                for (int j = 0; j < 4; ++j) {
                    float val = fmaf(al[j], LO_INV, am[j]);     // dot - c2/2
                    // argmax == argmin of distance; strict > keeps FIRST (lowest c) on ties
                    if (val > best[t][j]) { best[t][j] = val; bidx[t][j] = cidx; }
                }
            }
            __builtin_amdgcn_s_setprio(0);
        }
        // no barrier: double-buffer reuse is guarded by this wave's own vmcnt
    }

    // ---- butterfly argmax-merge across the 16 column-lanes of each row-group ----
#pragma unroll
    for (int t = 0; t < 4; ++t)
#pragma unroll
        for (int j = 0; j < 4; ++j) {
            float b = best[t][j]; int bi = bidx[t][j];
#pragma unroll
            for (int d = 1; d < 16; d <<= 1) {
                float ob = __shfl_xor(b, d, 64);
                int   oi = __shfl_xor(bi, d, 64);
                if (ob > b || (ob == b && oi < bi)) { b = ob; bi = oi; }
            }
            best[t][j] = b; bidx[t][j] = bi;
        }

    if ((lane & 15) == 0) {
        const int rg = lane >> 4;
#pragma unroll
        for (int t = 0; t < 4; ++t)
#pragma unroll
            for (int j = 0; j < 4; ++j) {
                int q = qbase + t * 16 + rg * 4 + j;
                ws_best[(size_t)slice * NQ + q] = best[t][j];
                ws_idx [(size_t)slice * NQ + q] = bidx[t][j];
            }
    }
}

// ---------------- merge slices (max of val, lower index on ties) ----------------
__global__ __launch_bounds__(256) void merge_kernel(const float* __restrict__ ws_best,
                                                    const int* __restrict__ ws_idx,
                                                    int* __restrict__ out) {
    int q = blockIdx.x * 256 + threadIdx.x;
    float b = ws_best[q]; int bi = ws_idx[q];
#pragma unroll
    for (int s = 1; s < NSLICE; ++s) {
        float v = ws_best[(size_t)s * NQ + q];
        int  vi = ws_idx[(size_t)s * NQ + q];
        if (v > b || (v == b && vi < bi)) { b = v; bi = vi; }
    }
    out[q] = bi;
}

extern "C" void kernel_launch(void* const* d_in, const int* in_sizes, int n_in,
                              void* d_out, int out_size, void* d_ws, size_t ws_size,
                              hipStream_t stream) {
    const float* patches = (const float*)d_in[0];   // [32768][64] fp32
    const float* vocab   = (const float*)d_in[1];   // [8192][64] fp32
    char* ws = (char*)d_ws;
    float*    c2    = (float*)ws;                                   // 32 KB
    _Float16* vhi   = (_Float16*)(ws + 32768);                      // 1 MB
    _Float16* vlo   = (_Float16*)(ws + 32768 + 1048576);            // 1 MB
    float*    wbest = (float*)(ws + 32768 + 2097152);               // 512 KB
    int*      widx  = (int*)  (ws + 32768 + 2097152 + 524288);      // 512 KB
    int* out = (int*)d_out;

    c2_kernel   <<<VOCAB / 256, 256, 0, stream>>>(vocab, c2);
    split_kernel<<<(VOCAB * DIM / 8) / 256, 256, 0, stream>>>(vocab, vhi, vlo);
    argmin_mfma <<<(NQ / QPB) * NSLICE, THREADS, 0, stream>>>(patches, vhi, vlo, c2, wbest, widx);
    merge_kernel<<<NQ / 256, 256, 0, stream>>>(wbest, widx, out);
}